// Round 6
// baseline (2907.513 us; speedup 1.0000x reference)
//
#include <hip/hip_runtime.h>
#include <hip/hip_bf16.h>
#include <math.h>

// Problem constants
#define D_MODEL 2048
#define D_FF    8192
#define MTOK    8192        // 4*2048 tokens
#define GSIZE   64
#define QBF     127.0f
#define EPSQ    1e-5f
#define W_NUMEL (D_FF * D_MODEL)        // 16,777,216 per weight
#define W_INV_NUMEL (1.0f / 16777216.0f)
#define NWAVE_PACK (W_NUMEL / 8 / 64)   // 32768 waves per wpack dispatch

typedef unsigned short u16;
typedef unsigned char  u8;
typedef unsigned int   u32;
typedef __attribute__((ext_vector_type(4))) float f32x4;
typedef __attribute__((ext_vector_type(4))) int   i32x4;
typedef __attribute__((ext_vector_type(4))) unsigned int u32x4;

// Async global->LDS, 16B per lane. GLOBAL SOURCE IS PER-LANE (must carry
// the tid*16 offset); LDS dest is wave-uniform base + lane*16.
// Round-5 bug: staging macros dropped the per-lane src offset -> all lanes
// fetched the same 16B -> garbage tiles. Fixed here.
__device__ __forceinline__ void gload_lds16(const void* g, void* l) {
    __builtin_amdgcn_global_load_lds(
        (const __attribute__((address_space(1))) unsigned int*)g,
        (__attribute__((address_space(3))) unsigned int*)l, 16, 0, 0);
}

// Supertiled XCD swizzle (round 4: cut g12 FETCH 2.1 GB -> 310 MB).
__device__ __forceinline__ void xcd_swizzle(int& bx, int& by, int gx, int gy) {
    int nwg  = gx * gy;
    int orig = by * gx + bx;
    int q = nwg >> 3;
    int xcd = orig & 7, loc = orig >> 3;
    int swz = xcd * q + loc;
    int bxi = swz & 7;
    int t   = swz >> 3;
    by = t % gy;
    bx = ((t / gy) << 3) + bxi;
}

// ---- int8 tile layout -------------------------------------------------
// 128 rows x 64 k x 1 B = 8 KB contiguous tile. Chunk swizzle
// c' = c ^ ((row>>1)&3) balances banks for per-quad ds_read_b128.
// Element (tile t, row r, k): off = t*8192 + r*64 + ((((k>>4)&3)^((r>>1)&3))<<4) + (k&15)

// ------- weight pack: fp32 [N,K] -> {-1,0,1} int8 swizzled tiles ---------
__global__ void wpack_kernel(const float* __restrict__ W, u8* __restrict__ Wb,
                             float* __restrict__ partial, int N, int K) {
    const int Gk  = K >> 6;
    const int cpr = K >> 3;                 // 8-elem chunks per row
    int idx = blockIdx.x * blockDim.x + threadIdx.x;   // grid is exact
    int row = idx / cpr;
    int ck  = idx - row * cpr;
    int k0  = ck << 3;
    const float* src = W + (size_t)row * K + k0;
    f32x4 w0 = *(const f32x4*)src;
    f32x4 w1 = *(const f32x4*)(src + 4);
    float s = 0.f;
    unsigned long long pk = 0ull;
    #pragma unroll
    for (int i = 0; i < 8; ++i) {
        float wv = (i < 4) ? w0[i] : w1[i - 4];
        s += fabsf(wv);
        int sv = (wv > 0.f) ? 1 : ((wv < 0.f) ? -1 : 0);
        pk |= ((unsigned long long)(u8)(signed char)sv) << (8 * i);
    }
    int nt = row >> 7, r = row & 127;
    int g = k0 >> 6, c = (k0 & 63) >> 4, j = k0 & 15;   // j in {0,8}
    size_t dst = ((size_t)(nt * Gk + g) << 13) + (size_t)r * 64
               + (size_t)((c ^ ((r >> 1) & 3)) << 4) + j;
    *(unsigned long long*)(Wb + dst) = pk;
    #pragma unroll
    for (int off = 32; off > 0; off >>= 1) s += __shfl_xor(s, off);
    if ((threadIdx.x & 63) == 0) partial[idx >> 6] = s;   // contention-free
}

// Sum 3 partial arrays -> wsum[0..2]. Grid = 3 blocks of 256.
__global__ void wsum_reduce(const float* __restrict__ partial, float* __restrict__ wsum) {
    __shared__ float red[4];
    const float* p = partial + (size_t)blockIdx.x * NWAVE_PACK;
    float s = 0.f;
    for (int i = threadIdx.x; i < NWAVE_PACK; i += 256) s += p[i];
    #pragma unroll
    for (int off = 32; off > 0; off >>= 1) s += __shfl_xor(s, off);
    if ((threadIdx.x & 63) == 0) red[threadIdx.x >> 6] = s;
    __syncthreads();
    if (threadIdx.x == 0) wsum[blockIdx.x] = red[0] + red[1] + red[2] + red[3];
}

// ---------------- per-group activation quant -> int8 swizzled tiles ------
__global__ void quant_kernel(const float* __restrict__ X, u8* __restrict__ Q,
                             float* __restrict__ SdivT, int M, int Gk) {
    const int K = Gk << 6;
    const int lane = threadIdx.x & 63;
    const int segs = K >> 8;
    int widx = (blockIdx.x * blockDim.x + threadIdx.x) >> 6;
    if (widx >= M * segs) return;
    int row = widx / segs;
    int seg = widx - row * segs;
    int k0 = (seg << 8) + lane * 4;
    f32x4 v = *(const f32x4*)(X + (size_t)row * K + k0);
    float a = fmaxf(fmaxf(fabsf(v[0]), fabsf(v[1])), fmaxf(fabsf(v[2]), fabsf(v[3])));
    a = fmaxf(a, __shfl_xor(a, 1));
    a = fmaxf(a, __shfl_xor(a, 2));
    a = fmaxf(a, __shfl_xor(a, 4));
    a = fmaxf(a, __shfl_xor(a, 8));          // max over 16-lane (64-elem) group
    float s = fmaxf(a, EPSQ);
    float rinv = QBF / s;
    u32 pk = 0;
    #pragma unroll
    for (int c = 0; c < 4; ++c) {
        float q = rintf(fminf(fmaxf(v[c] * rinv, -QBF), QBF));
        pk |= ((u32)(u8)(signed char)(int)q) << (8 * c);
    }
    int mt = row >> 7, r = row & 127;
    int gi = k0 >> 6;
    int c8 = (k0 & 63) >> 4, j0 = k0 & 15;   // j0 in {0,4,8,12}
    size_t dst = ((size_t)(mt * Gk + gi) << 13) + (size_t)r * 64
               + (size_t)((c8 ^ ((r >> 1) & 3)) << 4) + j0;
    *(u32*)(Q + dst) = pk;
    if ((lane & 15) == 0) SdivT[(size_t)gi * M + row] = s / QBF;
}

// ------------- fused up-projection: GEMM1+GEMM2 + silu*mul + requant -----
// int8 MFMA 16x16x64, dbuf LDS, G-loop unrolled x2 (even/odd buffers):
// all LDS addresses = 1 precomputed VGPR + compile-time immediate, scale
// regs alternate sfE/sfO (no copies), rescale = explicit cvt+fma only.
__global__ __launch_bounds__(256, 2)
void gemm_bit12(const u8* __restrict__ Aq, const float* __restrict__ SdivT,
                const u8* __restrict__ W1b, const u8* __restrict__ W2b,
                const float* __restrict__ wsum,
                u8* __restrict__ Qh, float* __restrict__ ShT,
                int G, int Mtot) {
    __shared__ __align__(16) u8 lsm[2][3][8192];   // dbuf x {A,B1,B2}; 48 KB

    const int tid  = threadIdx.x;
    const int lane = tid & 63;
    const int wid  = tid >> 6;
    const int quad = lane >> 4;
    const int l16  = lane & 15;
    const int wm = (wid & 1) * 64;
    const int wn = (wid >> 1) * 64;

    int bx = blockIdx.x, by = blockIdx.y;
    xcd_swizzle(bx, by, gridDim.x, gridDim.y);
    const int m0 = by * 128;

    const u8* gAp  = Aq  + ((size_t)by * G << 13);
    const u8* gB1p = W1b + ((size_t)bx * G << 13);
    const u8* gB2p = W2b + ((size_t)bx * G << 13);
    const int st0  = tid * 16;
    const int srow = m0 + wm + (quad << 2);        // scale rows: srow + mi*16 + r

    // per-thread LDS byte offsets (loop-invariant)
    int aoff[4], boff[4];
    #pragma unroll
    for (int mi = 0; mi < 4; ++mi) {
        int r = wm + mi * 16 + l16;
        aoff[mi] = r * 64 + ((quad ^ ((r >> 1) & 3)) << 4);
    }
    #pragma unroll
    for (int ni = 0; ni < 4; ++ni) {
        int rb = wn + ni * 16 + l16;
        boff[ni] = rb * 64 + ((quad ^ ((rb >> 1) & 3)) << 4);
    }
    const u8* lbase = &lsm[0][0][0];

    float acc1[4][4][4], acc2[4][4][4];
    #pragma unroll
    for (int i = 0; i < 4; ++i)
        #pragma unroll
        for (int j = 0; j < 4; ++j)
            #pragma unroll
            for (int r = 0; r < 4; ++r) { acc1[i][j][r] = 0.f; acc2[i][j][r] = 0.f; }
    const i32x4 izero = {0, 0, 0, 0};
    f32x4 sfE[4], sfO[4];

// NOTE: per-lane st0 on BOTH global src and LDS dst (round-5 fix).
#define STAGE12(BUF, GOFF) do { \
        gload_lds16(gAp  + (GOFF) + st0,        &lsm[BUF][0][st0]); \
        gload_lds16(gAp  + (GOFF) + st0 + 4096, &lsm[BUF][0][st0 + 4096]); \
        gload_lds16(gB1p + (GOFF) + st0,        &lsm[BUF][1][st0]); \
        gload_lds16(gB1p + (GOFF) + st0 + 4096, &lsm[BUF][1][st0 + 4096]); \
        gload_lds16(gB2p + (GOFF) + st0,        &lsm[BUF][2][st0]); \
        gload_lds16(gB2p + (GOFF) + st0 + 4096, &lsm[BUF][2][st0 + 4096]); \
    } while (0)

#define COMPUTE12(BOFF, SF) do { \
        i32x4 av[4]; \
        _Pragma("unroll") \
        for (int mi = 0; mi < 4; ++mi) \
            av[mi] = *(const i32x4*)(lbase + (BOFF) + aoff[mi]); \
        _Pragma("unroll") \
        for (int ni = 0; ni < 4; ++ni) { \
            i32x4 bv1 = *(const i32x4*)(lbase + (BOFF) + 8192  + boff[ni]); \
            i32x4 bv2 = *(const i32x4*)(lbase + (BOFF) + 16384 + boff[ni]); \
            _Pragma("unroll") \
            for (int mi = 0; mi < 4; ++mi) { \
                i32x4 d1 = __builtin_amdgcn_mfma_i32_16x16x64_i8(av[mi], bv1, izero, 0, 0, 0); \
                i32x4 d2 = __builtin_amdgcn_mfma_i32_16x16x64_i8(av[mi], bv2, izero, 0, 0, 0); \
                _Pragma("unroll") \
                for (int r = 0; r < 4; ++r) { \
                    acc1[mi][ni][r] = __builtin_fmaf((float)d1[r], SF[mi][r], acc1[mi][ni][r]); \
                    acc2[mi][ni][r] = __builtin_fmaf((float)d2[r], SF[mi][r], acc2[mi][ni][r]); \
                } \
            } \
        } \
    } while (0)

    // ---- prologue: stage g=0 into buf0, load its scales ----
    STAGE12(0, (size_t)0);
    {
        const float* sp = SdivT + srow;
        #pragma unroll
        for (int mi = 0; mi < 4; ++mi) sfE[mi] = *(const f32x4*)(sp + mi * 16);
    }
    __syncthreads();

    size_t goff = 0;                       // byte offset of tile g
    for (int g = 0; g < G; g += 2) {
        STAGE12(1, goff + 8192);           // tile g+1 -> buf1 (flies under compute)
        {
            const float* sp = SdivT + (size_t)(g + 1) * Mtot + srow;
            #pragma unroll
            for (int mi = 0; mi < 4; ++mi) sfO[mi] = *(const f32x4*)(sp + mi * 16);
        }
        COMPUTE12(0, sfE);
        __syncthreads();                   // buf1 staged; buf0 readers done
        if (g + 2 < G) {
            STAGE12(0, goff + 16384);      // tile g+2 -> buf0
            const float* sp = SdivT + (size_t)(g + 2) * Mtot + srow;
            #pragma unroll
            for (int mi = 0; mi < 4; ++mi) sfE[mi] = *(const f32x4*)(sp + mi * 16);
        }
        COMPUTE12(24576, sfO);
        __syncthreads();                   // buf0 staged; buf1 readers done
        goff += 16384;
    }
#undef STAGE12
#undef COMPUTE12

    // ---- epilogue: h = silu(y1)*y2, per-64-group int8 quant, tile out ----
    const float ws1 = wsum[0] * W_INV_NUMEL;
    const float ws2 = wsum[1] * W_INV_NUMEL;
    const int gl    = wn >> 6;                 // which of the 2 groups in this block
    const int gbase = bx * 2;                  // global d_ff group base
    u8* stg = &lsm[0][0][0];                   // 16 KB staging (loop ended w/ barrier)
    #pragma unroll
    for (int mi = 0; mi < 4; ++mi) {
        #pragma unroll
        for (int rr = 0; rr < 4; ++rr) {
            float h[4];
            #pragma unroll
            for (int ni = 0; ni < 4; ++ni) {
                float y1 = acc1[mi][ni][rr] * ws1;
                float y2 = acc2[mi][ni][rr] * ws2;
                h[ni] = (y1 / (1.f + expf(-y1))) * y2;   // silu(y1)*y2
            }
            float am = fmaxf(fmaxf(fabsf(h[0]), fabsf(h[1])), fmaxf(fabsf(h[2]), fabsf(h[3])));
            am = fmaxf(am, __shfl_xor(am, 1));
            am = fmaxf(am, __shfl_xor(am, 2));
            am = fmaxf(am, __shfl_xor(am, 4));
            am = fmaxf(am, __shfl_xor(am, 8));   // absmax over 4 ni x 16 lanes = 64 cols
            float s = fmaxf(am, EPSQ);
            float rinv = QBF / s;
            int rblk = wm + mi * 16 + quad * 4 + rr;
            #pragma unroll
            for (int ni = 0; ni < 4; ++ni) {
                float qv = rintf(fminf(fmaxf(h[ni] * rinv, -QBF), QBF));
                stg[gl * 8192 + rblk * 64 + ((ni ^ ((rblk >> 1) & 3)) << 4) + l16]
                    = (u8)(signed char)(int)qv;
            }
            if (l16 == 0) ShT[(size_t)(gbase + gl) * Mtot + m0 + rblk] = s / QBF;
        }
    }
    __syncthreads();
    // two 8 KB tiles (groups gbase, gbase+1) are contiguous in Qh
    size_t base = ((size_t)by * 128 + (size_t)gbase) << 13;   // bytes; Gff=128
    u32x4* dst = (u32x4*)(Qh + base);
    const u32x4* src = (const u32x4*)stg;
    #pragma unroll
    for (int i = 0; i < 4; ++i) dst[tid + i * 256] = src[tid + i * 256];
}

// ---------------- down-projection: (split-K) int8 bit-GEMM ---------------
// Same unrolled-x2 structure. gridDim.z == 1 -> plain stores; > 1 -> atomics.
__global__ __launch_bounds__(256, 3)
void gemm_bit3(const u8* __restrict__ Aq, const float* __restrict__ SdivT,
               const u8* __restrict__ Wb, const float* __restrict__ wsum,
               float* __restrict__ Y, int N, int G, int Mtot, int gPer) {
    __shared__ __align__(16) u8 lsm[2][2][8192];   // dbuf x {A,B}; 32 KB

    const int tid  = threadIdx.x;
    const int lane = tid & 63;
    const int wid  = tid >> 6;
    const int quad = lane >> 4;
    const int l16  = lane & 15;
    const int wm = (wid & 1) * 64;
    const int wn = (wid >> 1) * 64;

    int bx = blockIdx.x, by = blockIdx.y;
    xcd_swizzle(bx, by, gridDim.x, gridDim.y);
    const int m0 = by * 128;
    const int n0 = bx * 128;
    const int g0 = blockIdx.z * gPer;

    const u8* gAp = Aq + ((size_t)by * G << 13);
    const u8* gBp = Wb + ((size_t)bx * G << 13);
    const int st0  = tid * 16;
    const int srow = m0 + wm + (quad << 2);

    int aoff[4], boff[4];
    #pragma unroll
    for (int mi = 0; mi < 4; ++mi) {
        int r = wm + mi * 16 + l16;
        aoff[mi] = r * 64 + ((quad ^ ((r >> 1) & 3)) << 4);
    }
    #pragma unroll
    for (int ni = 0; ni < 4; ++ni) {
        int rb = wn + ni * 16 + l16;
        boff[ni] = rb * 64 + ((quad ^ ((rb >> 1) & 3)) << 4);
    }
    const u8* lbase = &lsm[0][0][0];

    float acc[4][4][4];
    #pragma unroll
    for (int i = 0; i < 4; ++i)
        #pragma unroll
        for (int j = 0; j < 4; ++j)
            #pragma unroll
            for (int r = 0; r < 4; ++r) acc[i][j][r] = 0.f;
    const i32x4 izero = {0, 0, 0, 0};
    f32x4 sfE[4], sfO[4];

// NOTE: per-lane st0 on BOTH global src and LDS dst (round-5 fix).
#define STAGE3K(BUF, GOFF) do { \
        gload_lds16(gAp + (GOFF) + st0,        &lsm[BUF][0][st0]); \
        gload_lds16(gAp + (GOFF) + st0 + 4096, &lsm[BUF][0][st0 + 4096]); \
        gload_lds16(gBp + (GOFF) + st0,        &lsm[BUF][1][st0]); \
        gload_lds16(gBp + (GOFF) + st0 + 4096, &lsm[BUF][1][st0 + 4096]); \
    } while (0)

#define COMPUTE3(BOFF, SF) do { \
        i32x4 av[4]; \
        _Pragma("unroll") \
        for (int mi = 0; mi < 4; ++mi) \
            av[mi] = *(const i32x4*)(lbase + (BOFF) + aoff[mi]); \
        _Pragma("unroll") \
        for (int ni = 0; ni < 4; ++ni) { \
            i32x4 bv = *(const i32x4*)(lbase + (BOFF) + 8192 + boff[ni]); \
            _Pragma("unroll") \
            for (int mi = 0; mi < 4; ++mi) { \
                i32x4 d = __builtin_amdgcn_mfma_i32_16x16x64_i8(av[mi], bv, izero, 0, 0, 0); \
                _Pragma("unroll") \
                for (int r = 0; r < 4; ++r) \
                    acc[mi][ni][r] = __builtin_fmaf((float)d[r], SF[mi][r], acc[mi][ni][r]); \
            } \
        } \
    } while (0)

    // prologue
    size_t goff = (size_t)g0 << 13;
    STAGE3K(0, goff);
    {
        const float* sp = SdivT + (size_t)g0 * Mtot + srow;
        #pragma unroll
        for (int mi = 0; mi < 4; ++mi) sfE[mi] = *(const f32x4*)(sp + mi * 16);
    }
    __syncthreads();

    const int gEnd = g0 + gPer;
    for (int g = g0; g < gEnd; g += 2) {
        STAGE3K(1, goff + 8192);
        {
            const float* sp = SdivT + (size_t)(g + 1) * Mtot + srow;
            #pragma unroll
            for (int mi = 0; mi < 4; ++mi) sfO[mi] = *(const f32x4*)(sp + mi * 16);
        }
        COMPUTE3(0, sfE);
        __syncthreads();
        if (g + 2 < gEnd) {
            STAGE3K(0, goff + 16384);
            const float* sp = SdivT + (size_t)(g + 2) * Mtot + srow;
            #pragma unroll
            for (int mi = 0; mi < 4; ++mi) sfE[mi] = *(const f32x4*)(sp + mi * 16);
        }
        COMPUTE3(16384, sfO);
        __syncthreads();
        goff += 16384;
    }
#undef STAGE3K
#undef COMPUTE3

    const float wsc = wsum[0] * W_INV_NUMEL;   // mean|w3| (pre-offset by caller)
    #pragma unroll
    for (int mi = 0; mi < 4; ++mi) {
        #pragma unroll
        for (int ni = 0; ni < 4; ++ni) {
            int col = n0 + wn + ni * 16 + l16;
            #pragma unroll
            for (int r = 0; r < 4; ++r) {
                int row = m0 + wm + mi * 16 + quad * 4 + r;
                size_t o = (size_t)row * N + col;
                float v = acc[mi][ni][r] * wsc;
                if (gridDim.z == 1) Y[o] = v;
                else atomicAdd(&Y[o], v);
            }
        }
    }
}

extern "C" void kernel_launch(void* const* d_in, const int* in_sizes, int n_in,
                              void* d_out, int out_size, void* d_ws, size_t ws_size,
                              hipStream_t stream) {
    const float* x  = (const float*)d_in[0];
    const float* w1 = (const float*)d_in[1];
    const float* w2 = (const float*)d_in[2];
    const float* w3 = (const float*)d_in[3];
    float* out = (float*)d_out;

    // ---- workspace: packed int8 weights (fixed) + chunked activations ----
    char* ws = (char*)d_ws;
    const size_t wbBytes = (size_t)W_NUMEL;            // 16 MB per packed weight
    float* wsum = (float*)ws;
    char* p = ws + 256;
    u8* w1b = (u8*)p;  p += wbBytes;
    u8* w2b = (u8*)p;  p += wbBytes;
    u8* w3b = (u8*)p;  p += wbBytes;
    float* partial = (float*)p;  p += (size_t)3 * NWAVE_PACK * 4;   // 384 KB
    size_t fixed = (size_t)(p - ws);

    // per-token: qx 2048 + sxT 128 + qh 8192 + shT 512 = 10,880 B
    const size_t perTok = (size_t)D_MODEL + 32 * 4 + (size_t)D_FF + 128 * 4;
    int Mc = 1024;
    for (int cand = MTOK; cand >= 1024; cand >>= 1) {
        if (fixed + perTok * (size_t)cand <= ws_size) { Mc = cand; break; }
    }
    const int nChunks = MTOK / Mc;

    u8*    qx  = (u8*)p;          p += (size_t)Mc * D_MODEL;
    float* sxT = (float*)p;       p += (size_t)Mc * 32 * 4;      // [32][Mc]
    u8*    qh  = (u8*)p;          p += (size_t)Mc * D_FF;
    float* shT = (float*)p;                                      // [128][Mc]

    // pack weights + contention-free |w| partials (weights read exactly once)
    wpack_kernel<<<W_NUMEL / 8 / 256, 256, 0, stream>>>(w1, w1b, partial + 0 * NWAVE_PACK, D_FF, D_MODEL);
    wpack_kernel<<<W_NUMEL / 8 / 256, 256, 0, stream>>>(w2, w2b, partial + 1 * NWAVE_PACK, D_FF, D_MODEL);
    wpack_kernel<<<W_NUMEL / 8 / 256, 256, 0, stream>>>(w3, w3b, partial + 2 * NWAVE_PACK, D_MODEL, D_FF);
    wsum_reduce<<<3, 256, 0, stream>>>(partial, wsum);

    const int S = MTOK / Mc;                    // split-K factor (1 when Mc=8192)
    const int gPer = (D_FF / GSIZE) / S;
    if (S > 1) (void)hipMemsetAsync(out, 0, (size_t)out_size, stream);

    for (int c = 0; c < nChunks; ++c) {
        const float* xc = x + (size_t)c * Mc * D_MODEL;
        float* outc     = out + (size_t)c * Mc * D_MODEL;

        quant_kernel<<<Mc * D_MODEL / 1024, 256, 0, stream>>>(xc, qx, sxT, Mc, D_MODEL / GSIZE);

        dim3 g12(D_FF / 128, Mc / 128);
        gemm_bit12<<<g12, 256, 0, stream>>>(qx, sxT, w1b, w2b, wsum, qh, shT,
                                            D_MODEL / GSIZE, Mc);

        dim3 g3(D_MODEL / 128, Mc / 128, S);
        gemm_bit3<<<g3, 256, 0, stream>>>(qh, shT, w3b, wsum + 2, outc,
                                          D_MODEL, D_FF / GSIZE, Mc, gPer);
    }
}

// Round 7
// 1057.367 us; speedup vs baseline: 2.7498x; 2.7498x over previous
//
#include <hip/hip_runtime.h>
#include <hip/hip_bf16.h>
#include <math.h>

// Problem constants
#define D_MODEL 2048
#define D_FF    8192
#define MTOK    8192        // 4*2048 tokens
#define GSIZE   64
#define QBF     127.0f
#define EPSQ    1e-5f
#define W_NUMEL (D_FF * D_MODEL)        // 16,777,216 per weight
#define W_INV_NUMEL (1.0f / 16777216.0f)
#define NWAVE_PACK (W_NUMEL / 8 / 64)   // 32768 waves per wpack dispatch

typedef unsigned short u16;
typedef unsigned char  u8;
typedef unsigned int   u32;
typedef __attribute__((ext_vector_type(4))) float f32x4;
typedef __attribute__((ext_vector_type(4))) int   i32x4;
typedef __attribute__((ext_vector_type(4))) unsigned int u32x4;

// Async global->LDS, 16B per lane. GLOBAL SOURCE IS PER-LANE (carries the
// tid*16 offset); LDS dest is wave-uniform base + lane*16.
__device__ __forceinline__ void gload_lds16(const void* g, void* l) {
    __builtin_amdgcn_global_load_lds(
        (const __attribute__((address_space(1))) unsigned int*)g,
        (__attribute__((address_space(3))) unsigned int*)l, 16, 0, 0);
}

// Supertiled XCD swizzle (round 4: cut g12 FETCH 2.1 GB -> 310 MB).
__device__ __forceinline__ void xcd_swizzle(int& bx, int& by, int gx, int gy) {
    int nwg  = gx * gy;
    int orig = by * gx + bx;
    int q = nwg >> 3;
    int xcd = orig & 7, loc = orig >> 3;
    int swz = xcd * q + loc;
    int bxi = swz & 7;
    int t   = swz >> 3;
    by = t % gy;
    bx = ((t / gy) << 3) + bxi;
}

// ---- int8 tile layout -------------------------------------------------
// 128 rows x 64 k x 1 B = 8 KB contiguous tile. Chunk swizzle
// c' = c ^ ((row>>1)&3) balances banks for per-quad ds_read_b128.
// Element (tile t, row r, k): off = t*8192 + r*64 + ((((k>>4)&3)^((r>>1)&3))<<4) + (k&15)

// ------- weight pack: fp32 [N,K] -> {-1,0,1} int8 swizzled tiles ---------
__global__ void wpack_kernel(const float* __restrict__ W, u8* __restrict__ Wb,
                             float* __restrict__ partial, int N, int K) {
    const int Gk  = K >> 6;
    const int cpr = K >> 3;                 // 8-elem chunks per row
    int idx = blockIdx.x * blockDim.x + threadIdx.x;   // grid is exact
    int row = idx / cpr;
    int ck  = idx - row * cpr;
    int k0  = ck << 3;
    const float* src = W + (size_t)row * K + k0;
    f32x4 w0 = *(const f32x4*)src;
    f32x4 w1 = *(const f32x4*)(src + 4);
    float s = 0.f;
    unsigned long long pk = 0ull;
    #pragma unroll
    for (int i = 0; i < 8; ++i) {
        float wv = (i < 4) ? w0[i] : w1[i - 4];
        s += fabsf(wv);
        int sv = (wv > 0.f) ? 1 : ((wv < 0.f) ? -1 : 0);
        pk |= ((unsigned long long)(u8)(signed char)sv) << (8 * i);
    }
    int nt = row >> 7, r = row & 127;
    int g = k0 >> 6, c = (k0 & 63) >> 4, j = k0 & 15;   // j in {0,8}
    size_t dst = ((size_t)(nt * Gk + g) << 13) + (size_t)r * 64
               + (size_t)((c ^ ((r >> 1) & 3)) << 4) + j;
    *(unsigned long long*)(Wb + dst) = pk;
    #pragma unroll
    for (int off = 32; off > 0; off >>= 1) s += __shfl_xor(s, off);
    if ((threadIdx.x & 63) == 0) partial[idx >> 6] = s;   // contention-free
}

// Sum 3 partial arrays -> wsum[0..2]. Grid = 3 blocks of 256.
__global__ void wsum_reduce(const float* __restrict__ partial, float* __restrict__ wsum) {
    __shared__ float red[4];
    const float* p = partial + (size_t)blockIdx.x * NWAVE_PACK;
    float s = 0.f;
    for (int i = threadIdx.x; i < NWAVE_PACK; i += 256) s += p[i];
    #pragma unroll
    for (int off = 32; off > 0; off >>= 1) s += __shfl_xor(s, off);
    if ((threadIdx.x & 63) == 0) red[threadIdx.x >> 6] = s;
    __syncthreads();
    if (threadIdx.x == 0) wsum[blockIdx.x] = red[0] + red[1] + red[2] + red[3];
}

// ---------------- per-group activation quant -> int8 swizzled tiles ------
__global__ void quant_kernel(const float* __restrict__ X, u8* __restrict__ Q,
                             float* __restrict__ SdivT, int M, int Gk) {
    const int K = Gk << 6;
    const int lane = threadIdx.x & 63;
    const int segs = K >> 8;
    int widx = (blockIdx.x * blockDim.x + threadIdx.x) >> 6;
    if (widx >= M * segs) return;
    int row = widx / segs;
    int seg = widx - row * segs;
    int k0 = (seg << 8) + lane * 4;
    f32x4 v = *(const f32x4*)(X + (size_t)row * K + k0);
    float a = fmaxf(fmaxf(fabsf(v[0]), fabsf(v[1])), fmaxf(fabsf(v[2]), fabsf(v[3])));
    a = fmaxf(a, __shfl_xor(a, 1));
    a = fmaxf(a, __shfl_xor(a, 2));
    a = fmaxf(a, __shfl_xor(a, 4));
    a = fmaxf(a, __shfl_xor(a, 8));          // max over 16-lane (64-elem) group
    float s = fmaxf(a, EPSQ);
    float rinv = QBF / s;
    u32 pk = 0;
    #pragma unroll
    for (int c = 0; c < 4; ++c) {
        float q = rintf(fminf(fmaxf(v[c] * rinv, -QBF), QBF));
        pk |= ((u32)(u8)(signed char)(int)q) << (8 * c);
    }
    int mt = row >> 7, r = row & 127;
    int gi = k0 >> 6;
    int c8 = (k0 & 63) >> 4, j0 = k0 & 15;   // j0 in {0,4,8,12}
    size_t dst = ((size_t)(mt * Gk + gi) << 13) + (size_t)r * 64
               + (size_t)((c8 ^ ((r >> 1) & 3)) << 4) + j0;
    *(u32*)(Q + dst) = pk;
    if ((lane & 15) == 0) SdivT[(size_t)gi * M + row] = s / QBF;
}

// ------------- fused up-projection: GEMM1+GEMM2 + silu*mul + requant -----
// int8 MFMA (16x16x64), double-buffered LDS, prefetch-before-compute.
// Round-4 verified structure; only change: rescale is direct elementwise
// cvt+fma into f32x4 acc (no vector temps, no unfused mul+add).
__global__ __launch_bounds__(256, 2)
void gemm_bit12(const u8* __restrict__ Aq, const float* __restrict__ SdivT,
                const u8* __restrict__ W1b, const u8* __restrict__ W2b,
                const float* __restrict__ wsum,
                u8* __restrict__ Qh, float* __restrict__ ShT,
                int G, int Mtot) {
    __shared__ __align__(16) u8 lsm[2][3][8192];   // dbuf x {A,B1,B2}; 48 KB

    const int tid  = threadIdx.x;
    const int lane = tid & 63;
    const int wid  = tid >> 6;
    const int quad = lane >> 4;
    const int l16  = lane & 15;
    const int wm = (wid & 1) * 64;
    const int wn = (wid >> 1) * 64;

    int bx = blockIdx.x, by = blockIdx.y;
    xcd_swizzle(bx, by, gridDim.x, gridDim.y);
    const int m0 = by * 128;

    const u8* gA  = Aq  + ((size_t)by * G << 13);
    const u8* gB1 = W1b + ((size_t)bx * G << 13);
    const u8* gB2 = W2b + ((size_t)bx * G << 13);
    const int srow = m0 + wm + (quad << 2);        // sf rows: srow + mi*16 + r

    f32x4 acc1[4][4], acc2[4][4];
    #pragma unroll
    for (int i = 0; i < 4; ++i)
        #pragma unroll
        for (int j = 0; j < 4; ++j) {
            acc1[i][j] = (f32x4){0.f, 0.f, 0.f, 0.f};
            acc2[i][j] = (f32x4){0.f, 0.f, 0.f, 0.f};
        }
    const i32x4 izero = {0, 0, 0, 0};
    f32x4 sfc[4], sfn[4];

    // ---- prologue: stage g=0 into buf0, load its scales ----
    {
        const u8* sA  = gA;  const u8* sB1 = gB1; const u8* sB2 = gB2;
        gload_lds16(sA  + tid * 16,        &lsm[0][0][tid * 16]);
        gload_lds16(sA  + 4096 + tid * 16, &lsm[0][0][4096 + tid * 16]);
        gload_lds16(sB1 + tid * 16,        &lsm[0][1][tid * 16]);
        gload_lds16(sB1 + 4096 + tid * 16, &lsm[0][1][4096 + tid * 16]);
        gload_lds16(sB2 + tid * 16,        &lsm[0][2][tid * 16]);
        gload_lds16(sB2 + 4096 + tid * 16, &lsm[0][2][4096 + tid * 16]);
        const float* sp = SdivT + srow;
        #pragma unroll
        for (int mi = 0; mi < 4; ++mi) sfc[mi] = *(const f32x4*)(sp + mi * 16);
        #pragma unroll
        for (int mi = 0; mi < 4; ++mi) sfn[mi] = sfc[mi];
    }
    __syncthreads();

    int cur = 0;
    for (int g = 0; g < G; ++g) {
        // ---- prefetch next K-tile BEFORE compute (loads fly under MFMA) ----
        if (g + 1 < G) {
            int nb = cur ^ 1;
            const u8* sA  = gA  + ((size_t)(g + 1) << 13);
            const u8* sB1 = gB1 + ((size_t)(g + 1) << 13);
            const u8* sB2 = gB2 + ((size_t)(g + 1) << 13);
            gload_lds16(sA  + tid * 16,        &lsm[nb][0][tid * 16]);
            gload_lds16(sA  + 4096 + tid * 16, &lsm[nb][0][4096 + tid * 16]);
            gload_lds16(sB1 + tid * 16,        &lsm[nb][1][tid * 16]);
            gload_lds16(sB1 + 4096 + tid * 16, &lsm[nb][1][4096 + tid * 16]);
            gload_lds16(sB2 + tid * 16,        &lsm[nb][2][tid * 16]);
            gload_lds16(sB2 + 4096 + tid * 16, &lsm[nb][2][4096 + tid * 16]);
            const float* sp = SdivT + (size_t)(g + 1) * Mtot + srow;
            #pragma unroll
            for (int mi = 0; mi < 4; ++mi) sfn[mi] = *(const f32x4*)(sp + mi * 16);
        }

        // ---- compute on current buffer ----
        const u8* LA  = &lsm[cur][0][0];
        const u8* LB1 = &lsm[cur][1][0];
        const u8* LB2 = &lsm[cur][2][0];
        i32x4 av[4];
        #pragma unroll
        for (int mi = 0; mi < 4; ++mi) {
            int r = wm + mi * 16 + l16;
            av[mi] = *(const i32x4*)(LA + r * 64 + ((quad ^ ((r >> 1) & 3)) << 4));
        }
        #pragma unroll
        for (int ni = 0; ni < 4; ++ni) {
            int rb = wn + ni * 16 + l16;
            int sw = (quad ^ ((rb >> 1) & 3)) << 4;
            i32x4 bv1 = *(const i32x4*)(LB1 + rb * 64 + sw);
            i32x4 bv2 = *(const i32x4*)(LB2 + rb * 64 + sw);
            #pragma unroll
            for (int mi = 0; mi < 4; ++mi) {
                i32x4 d1 = __builtin_amdgcn_mfma_i32_16x16x64_i8(av[mi], bv1, izero, 0, 0, 0);
                i32x4 d2 = __builtin_amdgcn_mfma_i32_16x16x64_i8(av[mi], bv2, izero, 0, 0, 0);
                #pragma unroll
                for (int r = 0; r < 4; ++r) {
                    acc1[mi][ni][r] = __builtin_fmaf((float)d1[r], sfc[mi][r], acc1[mi][ni][r]);
                    acc2[mi][ni][r] = __builtin_fmaf((float)d2[r], sfc[mi][r], acc2[mi][ni][r]);
                }
            }
        }
        __syncthreads();     // drains prefetch (had full compute phase to land)
        cur ^= 1;
        #pragma unroll
        for (int mi = 0; mi < 4; ++mi) sfc[mi] = sfn[mi];
    }

    // ---- epilogue: h = silu(y1)*y2, per-64-group int8 quant, tile out ----
    const float ws1 = wsum[0] * W_INV_NUMEL;
    const float ws2 = wsum[1] * W_INV_NUMEL;
    const int gl    = wn >> 6;                 // which of the 2 groups in this block
    const int gbase = bx * 2;                  // global d_ff group base
    u8* stg = &lsm[0][0][0];                   // 16 KB staging (loop ended w/ barrier)
    #pragma unroll
    for (int mi = 0; mi < 4; ++mi) {
        #pragma unroll
        for (int rr = 0; rr < 4; ++rr) {
            float h[4];
            #pragma unroll
            for (int ni = 0; ni < 4; ++ni) {
                float y1 = acc1[mi][ni][rr] * ws1;
                float y2 = acc2[mi][ni][rr] * ws2;
                h[ni] = (y1 / (1.f + expf(-y1))) * y2;   // silu(y1)*y2
            }
            float am = fmaxf(fmaxf(fabsf(h[0]), fabsf(h[1])), fmaxf(fabsf(h[2]), fabsf(h[3])));
            am = fmaxf(am, __shfl_xor(am, 1));
            am = fmaxf(am, __shfl_xor(am, 2));
            am = fmaxf(am, __shfl_xor(am, 4));
            am = fmaxf(am, __shfl_xor(am, 8));   // absmax over 4 ni x 16 lanes = 64 cols
            float s = fmaxf(am, EPSQ);
            float rinv = QBF / s;
            int rblk = wm + mi * 16 + quad * 4 + rr;
            #pragma unroll
            for (int ni = 0; ni < 4; ++ni) {
                float qv = rintf(fminf(fmaxf(h[ni] * rinv, -QBF), QBF));
                stg[gl * 8192 + rblk * 64 + ((ni ^ ((rblk >> 1) & 3)) << 4) + l16]
                    = (u8)(signed char)(int)qv;
            }
            if (l16 == 0) ShT[(size_t)(gbase + gl) * Mtot + m0 + rblk] = s / QBF;
        }
    }
    __syncthreads();
    // two 8 KB tiles (groups gbase, gbase+1) are contiguous in Qh
    size_t base = ((size_t)by * 128 + (size_t)gbase) << 13;   // bytes; Gff=128
    u32x4* dst = (u32x4*)(Qh + base);
    const u32x4* src = (const u32x4*)stg;
    #pragma unroll
    for (int i = 0; i < 4; ++i) dst[tid + i * 256] = src[tid + i * 256];
}

// ---------------- down-projection: (split-K) int8 bit-GEMM ---------------
// Round-4 verified structure + elementwise cvt+fma rescale.
// gridDim.z == 1 -> plain stores; > 1 -> fp32 atomicAdd onto zeroed output.
__global__ __launch_bounds__(256, 3)
void gemm_bit3(const u8* __restrict__ Aq, const float* __restrict__ SdivT,
               const u8* __restrict__ Wb, const float* __restrict__ wsum,
               float* __restrict__ Y, int N, int G, int Mtot, int gPer) {
    __shared__ __align__(16) u8 lsm[2][2][8192];   // dbuf x {A,B}; 32 KB

    const int tid  = threadIdx.x;
    const int lane = tid & 63;
    const int wid  = tid >> 6;
    const int quad = lane >> 4;
    const int l16  = lane & 15;
    const int wm = (wid & 1) * 64;
    const int wn = (wid >> 1) * 64;

    int bx = blockIdx.x, by = blockIdx.y;
    xcd_swizzle(bx, by, gridDim.x, gridDim.y);
    const int m0 = by * 128;
    const int n0 = bx * 128;
    const int g0 = blockIdx.z * gPer;

    const u8* gA = Aq + ((size_t)by * G << 13);
    const u8* gB = Wb + ((size_t)bx * G << 13);
    const int srow = m0 + wm + (quad << 2);

    f32x4 acc[4][4];
    #pragma unroll
    for (int i = 0; i < 4; ++i)
        #pragma unroll
        for (int j = 0; j < 4; ++j) acc[i][j] = (f32x4){0.f, 0.f, 0.f, 0.f};
    const i32x4 izero = {0, 0, 0, 0};
    f32x4 sfc[4], sfn[4];

    {
        const u8* sA = gA + ((size_t)g0 << 13);
        const u8* sB = gB + ((size_t)g0 << 13);
        gload_lds16(sA + tid * 16,        &lsm[0][0][tid * 16]);
        gload_lds16(sA + 4096 + tid * 16, &lsm[0][0][4096 + tid * 16]);
        gload_lds16(sB + tid * 16,        &lsm[0][1][tid * 16]);
        gload_lds16(sB + 4096 + tid * 16, &lsm[0][1][4096 + tid * 16]);
        const float* sp = SdivT + (size_t)g0 * Mtot + srow;
        #pragma unroll
        for (int mi = 0; mi < 4; ++mi) sfc[mi] = *(const f32x4*)(sp + mi * 16);
        #pragma unroll
        for (int mi = 0; mi < 4; ++mi) sfn[mi] = sfc[mi];
    }
    __syncthreads();

    int cur = 0;
    for (int g = g0; g < g0 + gPer; ++g) {
        if (g + 1 < g0 + gPer) {
            int nb = cur ^ 1;
            const u8* sA = gA + ((size_t)(g + 1) << 13);
            const u8* sB = gB + ((size_t)(g + 1) << 13);
            gload_lds16(sA + tid * 16,        &lsm[nb][0][tid * 16]);
            gload_lds16(sA + 4096 + tid * 16, &lsm[nb][0][4096 + tid * 16]);
            gload_lds16(sB + tid * 16,        &lsm[nb][1][tid * 16]);
            gload_lds16(sB + 4096 + tid * 16, &lsm[nb][1][4096 + tid * 16]);
            const float* sp = SdivT + (size_t)(g + 1) * Mtot + srow;
            #pragma unroll
            for (int mi = 0; mi < 4; ++mi) sfn[mi] = *(const f32x4*)(sp + mi * 16);
        }

        const u8* LA = &lsm[cur][0][0];
        const u8* LB = &lsm[cur][1][0];
        i32x4 av[4];
        #pragma unroll
        for (int mi = 0; mi < 4; ++mi) {
            int r = wm + mi * 16 + l16;
            av[mi] = *(const i32x4*)(LA + r * 64 + ((quad ^ ((r >> 1) & 3)) << 4));
        }
        #pragma unroll
        for (int ni = 0; ni < 4; ++ni) {
            int rb = wn + ni * 16 + l16;
            int sw = (quad ^ ((rb >> 1) & 3)) << 4;
            i32x4 bv = *(const i32x4*)(LB + rb * 64 + sw);
            #pragma unroll
            for (int mi = 0; mi < 4; ++mi) {
                i32x4 d = __builtin_amdgcn_mfma_i32_16x16x64_i8(av[mi], bv, izero, 0, 0, 0);
                #pragma unroll
                for (int r = 0; r < 4; ++r)
                    acc[mi][ni][r] = __builtin_fmaf((float)d[r], sfc[mi][r], acc[mi][ni][r]);
            }
        }
        __syncthreads();
        cur ^= 1;
        #pragma unroll
        for (int mi = 0; mi < 4; ++mi) sfc[mi] = sfn[mi];
    }

    const float wsc = wsum[0] * W_INV_NUMEL;   // mean|w3| (pre-offset by caller)
    #pragma unroll
    for (int mi = 0; mi < 4; ++mi) {
        #pragma unroll
        for (int ni = 0; ni < 4; ++ni) {
            int col = n0 + wn + ni * 16 + l16;
            #pragma unroll
            for (int r = 0; r < 4; ++r) {
                int row = m0 + wm + mi * 16 + quad * 4 + r;
                size_t o = (size_t)row * N + col;
                float v = acc[mi][ni][r] * wsc;
                if (gridDim.z == 1) Y[o] = v;
                else atomicAdd(&Y[o], v);
            }
        }
    }
}

extern "C" void kernel_launch(void* const* d_in, const int* in_sizes, int n_in,
                              void* d_out, int out_size, void* d_ws, size_t ws_size,
                              hipStream_t stream) {
    const float* x  = (const float*)d_in[0];
    const float* w1 = (const float*)d_in[1];
    const float* w2 = (const float*)d_in[2];
    const float* w3 = (const float*)d_in[3];
    float* out = (float*)d_out;

    // ---- workspace: packed int8 weights (fixed) + chunked activations ----
    char* ws = (char*)d_ws;
    const size_t wbBytes = (size_t)W_NUMEL;            // 16 MB per packed weight
    float* wsum = (float*)ws;
    char* p = ws + 256;
    u8* w1b = (u8*)p;  p += wbBytes;
    u8* w2b = (u8*)p;  p += wbBytes;
    u8* w3b = (u8*)p;  p += wbBytes;
    float* partial = (float*)p;  p += (size_t)3 * NWAVE_PACK * 4;   // 384 KB
    size_t fixed = (size_t)(p - ws);

    // per-token: qx 2048 + sxT 128 + qh 8192 + shT 512 = 10,880 B
    const size_t perTok = (size_t)D_MODEL + 32 * 4 + (size_t)D_FF + 128 * 4;
    int Mc = 1024;
    for (int cand = MTOK; cand >= 1024; cand >>= 1) {
        if (fixed + perTok * (size_t)cand <= ws_size) { Mc = cand; break; }
    }
    const int nChunks = MTOK / Mc;

    u8*    qx  = (u8*)p;          p += (size_t)Mc * D_MODEL;
    float* sxT = (float*)p;       p += (size_t)Mc * 32 * 4;      // [32][Mc]
    u8*    qh  = (u8*)p;          p += (size_t)Mc * D_FF;
    float* shT = (float*)p;                                      // [128][Mc]

    // pack weights + contention-free |w| partials (weights read exactly once)
    wpack_kernel<<<W_NUMEL / 8 / 256, 256, 0, stream>>>(w1, w1b, partial + 0 * NWAVE_PACK, D_FF, D_MODEL);
    wpack_kernel<<<W_NUMEL / 8 / 256, 256, 0, stream>>>(w2, w2b, partial + 1 * NWAVE_PACK, D_FF, D_MODEL);
    wpack_kernel<<<W_NUMEL / 8 / 256, 256, 0, stream>>>(w3, w3b, partial + 2 * NWAVE_PACK, D_MODEL, D_FF);
    wsum_reduce<<<3, 256, 0, stream>>>(partial, wsum);

    const int S = MTOK / Mc;                    // split-K factor (1 when Mc=8192)
    const int gPer = (D_FF / GSIZE) / S;
    if (S > 1) (void)hipMemsetAsync(out, 0, (size_t)out_size, stream);

    for (int c = 0; c < nChunks; ++c) {
        const float* xc = x + (size_t)c * Mc * D_MODEL;
        float* outc     = out + (size_t)c * Mc * D_MODEL;

        quant_kernel<<<Mc * D_MODEL / 1024, 256, 0, stream>>>(xc, qx, sxT, Mc, D_MODEL / GSIZE);

        dim3 g12(D_FF / 128, Mc / 128);
        gemm_bit12<<<g12, 256, 0, stream>>>(qx, sxT, w1b, w2b, wsum, qh, shT,
                                            D_MODEL / GSIZE, Mc);

        dim3 g3(D_MODEL / 128, Mc / 128, S);
        gemm_bit3<<<g3, 256, 0, stream>>>(qh, shT, w3b, wsum + 2, outc,
                                          D_MODEL, D_FF / GSIZE, Mc, gPer);
    }
}

// Round 8
// 1019.341 us; speedup vs baseline: 2.8523x; 1.0373x over previous
//
#include <hip/hip_runtime.h>
#include <hip/hip_bf16.h>
#include <math.h>

// Problem constants
#define D_MODEL 2048
#define D_FF    8192
#define MTOK    8192        // 4*2048 tokens
#define GSIZE   64
#define QBF     127.0f
#define EPSQ    1e-5f
#define W_NUMEL (D_FF * D_MODEL)        // 16,777,216 per weight
#define W_INV_NUMEL (1.0f / 16777216.0f)
#define NWAVE_PACK (W_NUMEL / 8 / 64)   // 32768 waves per wpack dispatch

typedef unsigned short u16;
typedef unsigned char  u8;
typedef unsigned int   u32;
typedef __attribute__((ext_vector_type(8))) short short8;   // 8 bf16 (A/B frag)
typedef __attribute__((ext_vector_type(4))) float f32x4;
typedef __attribute__((ext_vector_type(4))) unsigned int u32x4;
typedef __attribute__((ext_vector_type(4))) unsigned short u16x4;

// RNE float->bf16 (bit pattern)
__device__ __forceinline__ u16 f2bf(float f) {
    u32 u = __float_as_uint(f);
    return (u16)((u + 0x7FFFu + ((u >> 16) & 1u)) >> 16);
}

// Async global->LDS, 16B per lane. GLOBAL SOURCE IS PER-LANE (carries the
// tid*16 offset); LDS dest is wave-uniform base + lane*16.
__device__ __forceinline__ void gload_lds16(const void* g, void* l) {
    __builtin_amdgcn_global_load_lds(
        (const __attribute__((address_space(1))) unsigned int*)g,
        (__attribute__((address_space(3))) unsigned int*)l, 16, 0, 0);
}

// Supertiled XCD swizzle (round 4: cut g12 FETCH 2.1 GB -> 310 MB).
// Each XCD's contiguous 1/8 of blocks = one 8-wide bx column x all by.
__device__ __forceinline__ void xcd_swizzle(int& bx, int& by, int gx, int gy) {
    int nwg  = gx * gy;
    int orig = by * gx + bx;
    int q = nwg >> 3;
    int xcd = orig & 7, loc = orig >> 3;
    int swz = xcd * q + loc;
    int bxi = swz & 7;
    int t   = swz >> 3;
    by = t % gy;
    bx = ((t / gy) << 3) + bxi;
}

// ---- bf16 tile layout (verified rounds 0-2, bank-conflict-free) --------
// Tile = RB rows x 64 bf16. Row = 64 u16 = 8 chunks of 8 bf16 (16 B).
// Chunk swizzle c' = c ^ (r&7). Element (tile t, r, k), u16 units:
//   off = t*RB*64 + r*64 + (((k>>3) ^ (r&7))<<3) + (k&7)

// ------- weight pack: fp32 [N,K] -> +-1 bf16 swizzled tiles --------------
// rbits = log2(rows per tile): 6 for w1/w2 (64-row B tiles), 7 for w3.
// Per-wave |w| partials to scratch (contention-free), reduced separately.
__global__ void wpack_kernel(const float* __restrict__ W, u16* __restrict__ Wb,
                             float* __restrict__ partial, int K, int rbits) {
    const int Gk  = K >> 6;
    const int cpr = K >> 3;                 // 8-elem chunks per row
    int idx = blockIdx.x * blockDim.x + threadIdx.x;   // grid is exact
    int row = idx / cpr;
    int ck  = idx - row * cpr;
    int k0  = ck << 3;
    const float* src = W + (size_t)row * K + k0;
    f32x4 w0 = *(const f32x4*)src;
    f32x4 w1 = *(const f32x4*)(src + 4);
    float s = 0.f;
    unsigned hw[8];
    #pragma unroll
    for (int i = 0; i < 8; ++i) {
        float wv = (i < 4) ? w0[i] : w1[i - 4];
        s += fabsf(wv);
        hw[i] = (wv == 0.f) ? 0u : (0x3F80u | ((__float_as_uint(wv) >> 16) & 0x8000u));
    }
    u32x4 o;
    #pragma unroll
    for (int p = 0; p < 4; ++p) o[p] = hw[2 * p] | (hw[2 * p + 1] << 16);
    int nt = row >> rbits, r = row & ((1 << rbits) - 1);
    int g = k0 >> 6, c8 = (k0 & 63) >> 3;
    size_t dst = ((size_t)(nt * Gk + g) << (rbits + 6)) + (size_t)r * 64
               + (size_t)((c8 ^ (r & 7)) << 3);
    *(u32x4*)(Wb + dst) = o;
    #pragma unroll
    for (int off = 32; off > 0; off >>= 1) s += __shfl_xor(s, off);
    if ((threadIdx.x & 63) == 0) partial[idx >> 6] = s;   // contention-free
}

// Sum 3 partial arrays -> wsum[0..2]. Grid = 3 blocks of 256.
__global__ void wsum_reduce(const float* __restrict__ partial, float* __restrict__ wsum) {
    __shared__ float red[4];
    const float* p = partial + (size_t)blockIdx.x * NWAVE_PACK;
    float s = 0.f;
    for (int i = threadIdx.x; i < NWAVE_PACK; i += 256) s += p[i];
    #pragma unroll
    for (int off = 32; off > 0; off >>= 1) s += __shfl_xor(s, off);
    if ((threadIdx.x & 63) == 0) red[threadIdx.x >> 6] = s;
    __syncthreads();
    if (threadIdx.x == 0) wsum[blockIdx.x] = red[0] + red[1] + red[2] + red[3];
}

// ------- per-group activation quant -> SCALE-FOLDED bf16 tiles -----------
// a_out = round(clip(x*127/s)) * (s/127), stored bf16 (<=2^-9 rel err).
// This removes ALL per-group rescale work from the GEMM inner loops.
__global__ void quant_kernel(const float* __restrict__ X, u16* __restrict__ Q,
                             int M, int Gk) {
    const int K = Gk << 6;
    const int lane = threadIdx.x & 63;
    const int segs = K >> 8;
    int widx = (blockIdx.x * blockDim.x + threadIdx.x) >> 6;
    if (widx >= M * segs) return;
    int row = widx / segs;
    int seg = widx - row * segs;
    int k0 = (seg << 8) + lane * 4;
    f32x4 v = *(const f32x4*)(X + (size_t)row * K + k0);
    float a = fmaxf(fmaxf(fabsf(v[0]), fabsf(v[1])), fmaxf(fabsf(v[2]), fabsf(v[3])));
    a = fmaxf(a, __shfl_xor(a, 1));
    a = fmaxf(a, __shfl_xor(a, 2));
    a = fmaxf(a, __shfl_xor(a, 4));
    a = fmaxf(a, __shfl_xor(a, 8));          // max over 16-lane (64-elem) group
    float s = fmaxf(a, EPSQ);
    float rinv = QBF / s;
    float sdiv = s * (1.0f / QBF);
    u16x4 qo;
    #pragma unroll
    for (int c = 0; c < 4; ++c) {
        float q = rintf(fminf(fmaxf(v[c] * rinv, -QBF), QBF));
        qo[c] = f2bf(q * sdiv);
    }
    int mt = row >> 7, r = row & 127;
    int gi = k0 >> 6;
    int c8 = (k0 & 63) >> 3, j0 = k0 & 7;    // j0 in {0,4}
    size_t dst = ((size_t)(mt * Gk + gi) << 13) + (size_t)r * 64
               + (size_t)((c8 ^ (r & 7)) << 3) + j0;
    *(u16x4*)(Q + dst) = qo;
}

// ------------- fused up-projection: GEMM1+GEMM2 + silu*mul + requant -----
// bf16 MFMA (16x16x32) with C-in accumulation: ZERO inner-loop VALU.
// Tile 128M x 64N (one quant group wide); 4 waves stacked in M, each wave
// spans the full 64-col group -> epilogue absmax is an in-wave reduce.
// LDS: dbuf x {A 16K | B1 8K | B2 8K} = 64 KB -> 2 blocks/CU.
__global__ __launch_bounds__(256, 2)
void gemm_bit12(const u16* __restrict__ Aq,
                const u16* __restrict__ W1b, const u16* __restrict__ W2b,
                const float* __restrict__ wsum,
                u16* __restrict__ Qh, int G, int Mtot) {
    __shared__ __align__(16) u8 lsm[2][32768];   // A@0, B1@16384, B2@24576

    const int tid  = threadIdx.x;
    const int lane = tid & 63;
    const int wid  = tid >> 6;
    const int quad = lane >> 4;
    const int l16  = lane & 15;
    const int wm   = wid * 32;               // 4 waves x 32 rows

    int bx = blockIdx.x, by = blockIdx.y;
    xcd_swizzle(bx, by, gridDim.x, gridDim.y);

    const u8* gA  = (const u8*)Aq  + ((size_t)by * G << 14);   // 16 KB tiles
    const u8* gB1 = (const u8*)W1b + ((size_t)bx * G << 13);   // 8 KB tiles
    const u8* gB2 = (const u8*)W2b + ((size_t)bx * G << 13);
    const int st0 = tid * 16;

    // LDS byte offsets (loop-invariant): row stride 128 B, chunk 16 B
    int aoff[2][2], boff[4][2];
    #pragma unroll
    for (int mi = 0; mi < 2; ++mi)
        #pragma unroll
        for (int ks = 0; ks < 2; ++ks) {
            int r = wm + mi * 16 + l16;
            aoff[mi][ks] = r * 128 + (((ks * 4 + quad) ^ (r & 7)) << 4);
        }
    #pragma unroll
    for (int ni = 0; ni < 4; ++ni)
        #pragma unroll
        for (int ks = 0; ks < 2; ++ks) {
            int rb = ni * 16 + l16;
            boff[ni][ks] = rb * 128 + (((ks * 4 + quad) ^ (rb & 7)) << 4);
        }

    f32x4 acc1[2][4], acc2[2][4];
    #pragma unroll
    for (int i = 0; i < 2; ++i)
        #pragma unroll
        for (int j = 0; j < 4; ++j) {
            acc1[i][j] = (f32x4){0.f, 0.f, 0.f, 0.f};
            acc2[i][j] = (f32x4){0.f, 0.f, 0.f, 0.f};
        }

    // ---- prologue: stage g=0 into buf0 ----
    {
        #pragma unroll
        for (int i = 0; i < 4; ++i)
            gload_lds16(gA + st0 + i * 4096, &lsm[0][st0 + i * 4096]);
        #pragma unroll
        for (int i = 0; i < 2; ++i) {
            gload_lds16(gB1 + st0 + i * 4096, &lsm[0][16384 + st0 + i * 4096]);
            gload_lds16(gB2 + st0 + i * 4096, &lsm[0][24576 + st0 + i * 4096]);
        }
    }
    __syncthreads();

    int cur = 0;
    for (int g = 0; g < G; ++g) {
        if (g + 1 < G) {                      // prefetch next tile set
            int nb = cur ^ 1;
            const u8* sA  = gA  + ((size_t)(g + 1) << 14);
            const u8* sB1 = gB1 + ((size_t)(g + 1) << 13);
            const u8* sB2 = gB2 + ((size_t)(g + 1) << 13);
            #pragma unroll
            for (int i = 0; i < 4; ++i)
                gload_lds16(sA + st0 + i * 4096, &lsm[nb][st0 + i * 4096]);
            #pragma unroll
            for (int i = 0; i < 2; ++i) {
                gload_lds16(sB1 + st0 + i * 4096, &lsm[nb][16384 + st0 + i * 4096]);
                gload_lds16(sB2 + st0 + i * 4096, &lsm[nb][24576 + st0 + i * 4096]);
            }
        }

        const u8* L = lsm[cur];
        short8 a[2][2];
        #pragma unroll
        for (int mi = 0; mi < 2; ++mi)
            #pragma unroll
            for (int ks = 0; ks < 2; ++ks)
                a[mi][ks] = *(const short8*)(L + aoff[mi][ks]);
        #pragma unroll
        for (int ni = 0; ni < 4; ++ni) {
            short8 b10 = *(const short8*)(L + 16384 + boff[ni][0]);
            short8 b11 = *(const short8*)(L + 16384 + boff[ni][1]);
            short8 b20 = *(const short8*)(L + 24576 + boff[ni][0]);
            short8 b21 = *(const short8*)(L + 24576 + boff[ni][1]);
            #pragma unroll
            for (int mi = 0; mi < 2; ++mi) {
                acc1[mi][ni] = __builtin_amdgcn_mfma_f32_16x16x32_bf16(a[mi][0], b10, acc1[mi][ni], 0, 0, 0);
                acc1[mi][ni] = __builtin_amdgcn_mfma_f32_16x16x32_bf16(a[mi][1], b11, acc1[mi][ni], 0, 0, 0);
                acc2[mi][ni] = __builtin_amdgcn_mfma_f32_16x16x32_bf16(a[mi][0], b20, acc2[mi][ni], 0, 0, 0);
                acc2[mi][ni] = __builtin_amdgcn_mfma_f32_16x16x32_bf16(a[mi][1], b21, acc2[mi][ni], 0, 0, 0);
            }
        }
        __syncthreads();
        cur ^= 1;
    }

    // ---- epilogue: h = silu(y1)*y2, per-64-group quant -> scaled bf16 ----
    const float ws1 = wsum[0] * W_INV_NUMEL;
    const float ws2 = wsum[1] * W_INV_NUMEL;
    u16* stg = (u16*)lsm;                     // 16 KB staging tile
    #pragma unroll
    for (int mi = 0; mi < 2; ++mi) {
        #pragma unroll
        for (int rr = 0; rr < 4; ++rr) {
            float h[4];
            #pragma unroll
            for (int ni = 0; ni < 4; ++ni) {
                float y1 = acc1[mi][ni][rr] * ws1;
                float y2 = acc2[mi][ni][rr] * ws2;
                h[ni] = (y1 / (1.f + expf(-y1))) * y2;   // silu(y1)*y2
            }
            float am = fmaxf(fmaxf(fabsf(h[0]), fabsf(h[1])), fmaxf(fabsf(h[2]), fabsf(h[3])));
            am = fmaxf(am, __shfl_xor(am, 1));
            am = fmaxf(am, __shfl_xor(am, 2));
            am = fmaxf(am, __shfl_xor(am, 4));
            am = fmaxf(am, __shfl_xor(am, 8));   // absmax over 4 ni x 16 lanes = 64 cols
            float s = fmaxf(am, EPSQ);
            float rinv = QBF / s;
            float sdiv = s * (1.0f / QBF);
            int rblk = wm + mi * 16 + quad * 4 + rr;
            #pragma unroll
            for (int ni = 0; ni < 4; ++ni) {
                float qv = rintf(fminf(fmaxf(h[ni] * rinv, -QBF), QBF));
                int c8 = ni * 2 + (l16 >> 3);
                stg[rblk * 64 + ((c8 ^ (rblk & 7)) << 3) + (l16 & 7)] = f2bf(qv * sdiv);
            }
        }
    }
    __syncthreads();
    // one 16 KB tile (M-tile by, group bx) -> Qh
    u32x4* dst = (u32x4*)(Qh + (((size_t)by * 128 + bx) << 13));
    const u32x4* src = (const u32x4*)stg;
    #pragma unroll
    for (int i = 0; i < 4; ++i) dst[tid + i * 256] = src[tid + i * 256];
}

// ---------------- down-projection: bf16 bit-GEMM (128x128 tile) ----------
// A = scale-folded qh tiles; B = +-1 w3 tiles; C-in accumulation; epilogue
// scales by mean|w3| and stores.
__global__ __launch_bounds__(256, 2)
void gemm_bit3(const u16* __restrict__ Aq, const u16* __restrict__ Wb,
               const float* __restrict__ wsum, float* __restrict__ Y,
               int N, int G, int Mtot) {
    __shared__ __align__(16) u8 lsm[2][32768];   // A@0 (16K), B@16384 (16K)

    const int tid  = threadIdx.x;
    const int lane = tid & 63;
    const int wid  = tid >> 6;
    const int quad = lane >> 4;
    const int l16  = lane & 15;
    const int wm = (wid & 1) * 64;
    const int wn = (wid >> 1) * 64;

    int bx = blockIdx.x, by = blockIdx.y;
    xcd_swizzle(bx, by, gridDim.x, gridDim.y);
    const int m0 = by * 128;
    const int n0 = bx * 128;

    const u8* gA = (const u8*)Aq + ((size_t)by * G << 14);   // 16 KB tiles
    const u8* gB = (const u8*)Wb + ((size_t)bx * G << 14);   // 16 KB tiles
    const int st0 = tid * 16;

    int aoff[4][2], boff[4][2];
    #pragma unroll
    for (int mi = 0; mi < 4; ++mi)
        #pragma unroll
        for (int ks = 0; ks < 2; ++ks) {
            int r = wm + mi * 16 + l16;
            aoff[mi][ks] = r * 128 + (((ks * 4 + quad) ^ (r & 7)) << 4);
        }
    #pragma unroll
    for (int ni = 0; ni < 4; ++ni)
        #pragma unroll
        for (int ks = 0; ks < 2; ++ks) {
            int rb = wn + ni * 16 + l16;
            boff[ni][ks] = rb * 128 + (((ks * 4 + quad) ^ (rb & 7)) << 4);
        }

    f32x4 acc[4][4];
    #pragma unroll
    for (int i = 0; i < 4; ++i)
        #pragma unroll
        for (int j = 0; j < 4; ++j) acc[i][j] = (f32x4){0.f, 0.f, 0.f, 0.f};

    {   // prologue: stage g=0
        #pragma unroll
        for (int i = 0; i < 4; ++i) {
            gload_lds16(gA + st0 + i * 4096, &lsm[0][st0 + i * 4096]);
            gload_lds16(gB + st0 + i * 4096, &lsm[0][16384 + st0 + i * 4096]);
        }
    }
    __syncthreads();

    int cur = 0;
    for (int g = 0; g < G; ++g) {
        if (g + 1 < G) {
            int nb = cur ^ 1;
            const u8* sA = gA + ((size_t)(g + 1) << 14);
            const u8* sB = gB + ((size_t)(g + 1) << 14);
            #pragma unroll
            for (int i = 0; i < 4; ++i) {
                gload_lds16(sA + st0 + i * 4096, &lsm[nb][st0 + i * 4096]);
                gload_lds16(sB + st0 + i * 4096, &lsm[nb][16384 + st0 + i * 4096]);
            }
        }

        const u8* L = lsm[cur];
        short8 a[4][2];
        #pragma unroll
        for (int mi = 0; mi < 4; ++mi)
            #pragma unroll
            for (int ks = 0; ks < 2; ++ks)
                a[mi][ks] = *(const short8*)(L + aoff[mi][ks]);
        #pragma unroll
        for (int ni = 0; ni < 4; ++ni) {
            short8 b0 = *(const short8*)(L + 16384 + boff[ni][0]);
            short8 b1 = *(const short8*)(L + 16384 + boff[ni][1]);
            #pragma unroll
            for (int mi = 0; mi < 4; ++mi) {
                acc[mi][ni] = __builtin_amdgcn_mfma_f32_16x16x32_bf16(a[mi][0], b0, acc[mi][ni], 0, 0, 0);
                acc[mi][ni] = __builtin_amdgcn_mfma_f32_16x16x32_bf16(a[mi][1], b1, acc[mi][ni], 0, 0, 0);
            }
        }
        __syncthreads();
        cur ^= 1;
    }

    const float wsc = wsum[0] * W_INV_NUMEL;   // mean|w3| (pre-offset by caller)
    #pragma unroll
    for (int mi = 0; mi < 4; ++mi) {
        #pragma unroll
        for (int ni = 0; ni < 4; ++ni) {
            int col = n0 + wn + ni * 16 + l16;
            #pragma unroll
            for (int r = 0; r < 4; ++r) {
                int row = m0 + wm + mi * 16 + quad * 4 + r;
                Y[(size_t)row * N + col] = acc[mi][ni][r] * wsc;
            }
        }
    }
}

extern "C" void kernel_launch(void* const* d_in, const int* in_sizes, int n_in,
                              void* d_out, int out_size, void* d_ws, size_t ws_size,
                              hipStream_t stream) {
    const float* x  = (const float*)d_in[0];
    const float* w1 = (const float*)d_in[1];
    const float* w2 = (const float*)d_in[2];
    const float* w3 = (const float*)d_in[3];
    float* out = (float*)d_out;

    // ---- workspace: packed bf16 weights (fixed) + chunked activations ----
    char* ws = (char*)d_ws;
    const size_t wbBytes = (size_t)W_NUMEL * 2;        // 32 MB per packed weight
    float* wsum = (float*)ws;
    char* p = ws + 256;
    u16* w1b = (u16*)p;  p += wbBytes;
    u16* w2b = (u16*)p;  p += wbBytes;
    u16* w3b = (u16*)p;  p += wbBytes;
    size_t fixed = (size_t)(p - ws);

    // per-token: qx 4096 + qh 16384 = 20,480 B (scales folded into bf16!)
    const size_t perTok = (size_t)D_MODEL * 2 + (size_t)D_FF * 2;
    int Mc = 1024;
    for (int cand = MTOK; cand >= 1024; cand >>= 1) {
        if (fixed + perTok * (size_t)cand <= ws_size) { Mc = cand; break; }
    }
    const int nChunks = MTOK / Mc;

    u16* qx = (u16*)p;            p += (size_t)Mc * D_MODEL * 2;
    u16* qh = (u16*)p;
    // |w| partials overlap qx (prep finishes before quant writes qx)
    float* partial = (float*)qx;

    // pack weights + contention-free |w| partials (weights read exactly once)
    wpack_kernel<<<W_NUMEL / 8 / 256, 256, 0, stream>>>(w1, w1b, partial + 0 * NWAVE_PACK, D_MODEL, 6);
    wpack_kernel<<<W_NUMEL / 8 / 256, 256, 0, stream>>>(w2, w2b, partial + 1 * NWAVE_PACK, D_MODEL, 6);
    wpack_kernel<<<W_NUMEL / 8 / 256, 256, 0, stream>>>(w3, w3b, partial + 2 * NWAVE_PACK, D_FF, 7);
    wsum_reduce<<<3, 256, 0, stream>>>(partial, wsum);

    for (int c = 0; c < nChunks; ++c) {
        const float* xc = x + (size_t)c * Mc * D_MODEL;
        float* outc     = out + (size_t)c * Mc * D_MODEL;

        quant_kernel<<<Mc * D_MODEL / 1024, 256, 0, stream>>>(xc, qx, Mc, D_MODEL / GSIZE);

        dim3 g12(D_FF / 64, Mc / 128);           // 128 x (Mc/128) blocks
        gemm_bit12<<<g12, 256, 0, stream>>>(qx, w1b, w2b, wsum, qh,
                                            D_MODEL / GSIZE, Mc);

        dim3 g3(D_MODEL / 128, Mc / 128);        // 16 x (Mc/128) blocks
        gemm_bit3<<<g3, 256, 0, stream>>>(qh, w3b, wsum + 2, outc,
                                          D_MODEL, D_FF / GSIZE, Mc);
    }
}